// Round 4
// baseline (1160.588 us; speedup 1.0000x reference)
//
#include <hip/hip_runtime.h>

typedef unsigned long long u64;
typedef unsigned int u32;
typedef unsigned short u16;

#define V_ 1000000
#define STEPS_ 10
#define EPS_ 1e-5f
#define MARGIN_ 0.02f
#define NBLK_ 128

// ---------------------------------------------------------------------------
// Packed (value, ~idx) so u64 max == argmax with lowest-index tie-break.
// ---------------------------------------------------------------------------
__device__ __forceinline__ u64 pack_best(float v, int idx) {
    u32 u = __float_as_uint(v);
    u = (u & 0x80000000u) ? ~u : (u | 0x80000000u);
    return ((u64)u << 32) | (u64)(~(u32)idx);
}
__device__ __forceinline__ int unpack_idx(u64 p) { return (int)(~(u32)p); }
__device__ __forceinline__ float unpack_val(u64 p) {
    u32 hi = (u32)(p >> 32);
    return __uint_as_float((hi & 0x80000000u) ? (hi ^ 0x80000000u) : ~hi);
}
__device__ __forceinline__ u64 shfl_xor_u64(u64 v, int m) {
    u32 lo = (u32)v, hi = (u32)(v >> 32);
    lo = (u32)__shfl_xor((int)lo, m);
    hi = (u32)__shfl_xor((int)hi, m);
    return ((u64)hi << 32) | lo;
}
__device__ __forceinline__ u16 f2bf(float f) {
    u32 u = __float_as_uint(f);
    u += 0x7fffu + ((u >> 16) & 1u);
    return (u16)(u >> 16);
}
__device__ __forceinline__ float bf_lo(u32 u) { return __uint_as_float(u << 16); }
__device__ __forceinline__ float bf_hi(u32 u) { return __uint_as_float(u & 0xffff0000u); }

// ---------------------------------------------------------------------------
// Grid barrier: monotonic device-scope counter, zeroed once per launch by
// init_kernel. All NBLK_ blocks are co-resident (128 blocks on 256 CUs), so
// spinning is safe. target = (#barriers completed so far + 1) * NBLK_.
// ---------------------------------------------------------------------------
__device__ __forceinline__ void grid_barrier(u32* cnt, u32 target) {
    __syncthreads();
    if (threadIdx.x == 0) {
        __threadfence();
        __hip_atomic_fetch_add(cnt, 1u, __ATOMIC_ACQ_REL, __HIP_MEMORY_SCOPE_AGENT);
        while (__hip_atomic_load(cnt, __ATOMIC_ACQUIRE, __HIP_MEMORY_SCOPE_AGENT) < target) {
            __builtin_amdgcn_s_sleep(2);
        }
    }
    __syncthreads();
}

// ---------------------------------------------------------------------------
// Exact argmax resolve (blockDim=256): approx block-bests (bf16 logits) in
// cand[2048]; rescore all candidates within MARGIN of the max with fp32.
// ---------------------------------------------------------------------------
__device__ int resolve_argmax(const u64* __restrict__ cand,
                              const float* __restrict__ item_emb,
                              const float* __restrict__ y_last,
                              const float* __restrict__ lnw,
                              const float* __restrict__ lnb,
                              float* s_xl, int* s_list, u64* s_wm,
                              int* s_cnt, u64* s_best)
{
    const int tid = threadIdx.x;
    if (tid < 64) {
        float v = y_last[tid];
        float m = v;
        #pragma unroll
        for (int o = 1; o < 64; o <<= 1) m += __shfl_xor(m, o);
        m *= (1.f / 64.f);
        float df = v - m;
        float var = df * df;
        #pragma unroll
        for (int o = 1; o < 64; o <<= 1) var += __shfl_xor(var, o);
        var *= (1.f / 64.f);
        s_xl[tid] = df * (1.f / sqrtf(var + EPS_)) * lnw[tid] + lnb[tid];
    }
    if (tid == 0) { *s_cnt = 0; *s_best = 0ull; }
    __syncthreads();

    u64 m = 0ull;
    for (int i = tid; i < 2048; i += 256) { u64 c = cand[i]; if (c > m) m = c; }
    #pragma unroll
    for (int o = 1; o < 64; o <<= 1) { u64 x = shfl_xor_u64(m, o); if (x > m) m = x; }
    if ((tid & 63) == 0) s_wm[tid >> 6] = m;
    __syncthreads();
    if (tid == 0) {
        u64 b = s_wm[0];
        for (int i = 1; i < 4; i++) if (s_wm[i] > b) b = s_wm[i];
        s_wm[0] = b;
    }
    __syncthreads();

    float thr = unpack_val(s_wm[0]) - MARGIN_;
    for (int i = tid; i < 2048; i += 256) {
        if (unpack_val(cand[i]) >= thr) {
            int p = atomicAdd(s_cnt, 1);
            if (p < 64) s_list[p] = unpack_idx(cand[i]);
        }
    }
    __syncthreads();
    int n = *s_cnt; if (n > 64) n = 64;
    const int wid = tid >> 6, lane = tid & 63;
    for (int c = wid; c < n; c += 4) {
        int row = s_list[c];
        float p = s_xl[lane] * item_emb[(size_t)row * 64 + lane];
        #pragma unroll
        for (int o = 1; o < 64; o <<= 1) p += __shfl_xor(p, o);
        if (lane == 0) atomicMax(s_best, pack_best(p, row));
    }
    __syncthreads();
    return unpack_idx(*s_best);
}

__global__ void init_kernel(u32* bar) { if (threadIdx.x == 0) *bar = 0u; }

// ---------------------------------------------------------------------------
// Fused per-step encoder: 128 blocks x 256, 3 internal grid barriers.
//   Phase A (all blocks redundant): resolve argmax, build x, layer-0
//     attention + LN1 (kept in LDS), FFN1-l0 distributed (16 units/block).
//   barrier -> Phase B: FFN2-l0 distributed (d = bid&63, row-half = bid>>6).
//   barrier -> Phase C (redundant): LN2-l0, layer-1 attention last row only,
//     LN1, FFN1-l1 distributed.
//   barrier -> Phase D: blocks 0..63 compute y_last[d].
// ---------------------------------------------------------------------------
__global__ __launch_bounds__(256) void encoder_kernel(
    const float* __restrict__ ht, const float* __restrict__ item_emb,
    const float* __restrict__ pos_emb,
    const float* __restrict__ ipw, const float* __restrict__ ipb,
    const float* __restrict__ ow,  const float* __restrict__ ob,
    const float* __restrict__ l1w, const float* __restrict__ l1b,
    const float* __restrict__ l2w, const float* __restrict__ l2b,
    const float* __restrict__ f1w, const float* __restrict__ f1b,
    const float* __restrict__ f2w, const float* __restrict__ f2b,
    const u64* __restrict__ cand, int* __restrict__ gen_idx,
    float* __restrict__ gen_out, float* __restrict__ y0,
    float* __restrict__ y_last, float* __restrict__ hbuf,
    u32* __restrict__ bar, int t)
{
    const int S = t + 1;
    const int tid = threadIdx.x;
    const int bid = blockIdx.x;
    const u32 base = (u32)(3 * t) * NBLK_;

    __shared__ float x[640], qkv[1920], att[400], o_[640], y2[640], xps[640];
    __shared__ float rm[10], rr[10], xl[64];
    __shared__ int list[64], cnt;
    __shared__ u64 wm[4], best;

    // ---------------- Phase A ----------------
    int newidx = -1;
    if (t > 0) {
        newidx = resolve_argmax(cand, item_emb, y_last, l2w + 64, l2b + 64,
                                xl, list, wm, &cnt, &best);
        if (bid == 0 && tid == 0) {
            gen_idx[t - 1] = newidx;
            gen_out[t - 1] = (float)newidx;
        }
    }
    __syncthreads();

    for (int i = tid; i < S * 64; i += 256) {
        int s = i >> 6, d = i & 63;
        float basev;
        if (s == 0) basev = ht[d];
        else {
            int gi = (s == t) ? newidx : gen_idx[s - 1];
            basev = item_emb[(size_t)gi * 64 + d];
        }
        x[i] = basev + pos_emb[i];
    }
    __syncthreads();

    for (int i = tid; i < S * 192; i += 256) {
        int s = i / 192, j = i % 192;
        float acc = ipb[j];
        const float4* wr = (const float4*)(ipw + j * 64);
        const float4* xr = (const float4*)(x + s * 64);
        #pragma unroll
        for (int k = 0; k < 16; k++) {
            float4 w4 = wr[k], xv = xr[k];
            acc += w4.x * xv.x + w4.y * xv.y + w4.z * xv.z + w4.w * xv.w;
        }
        qkv[i] = acc;
    }
    __syncthreads();

    for (int i = tid; i < 4 * S * S; i += 256) {
        int h = i / (S * S), r = i % (S * S);
        int si = r / S, ti = r % S;
        const float* qr = qkv + si * 192 + h * 16;
        const float* kr = qkv + ti * 192 + 64 + h * 16;
        float acc = 0.f;
        #pragma unroll
        for (int k = 0; k < 16; k++) acc += qr[k] * kr[k];
        att[(h * S + si) * S + ti] = acc * 0.25f;
    }
    __syncthreads();

    for (int i = tid; i < 4 * S; i += 256) {
        float* row = att + i * S;
        float mx = row[0];
        for (int j = 1; j < S; j++) mx = fmaxf(mx, row[j]);
        float sm = 0.f;
        for (int j = 0; j < S; j++) { float e = expf(row[j] - mx); row[j] = e; sm += e; }
        float inv = 1.f / sm;
        for (int j = 0; j < S; j++) row[j] *= inv;
    }
    __syncthreads();

    for (int i = tid; i < S * 64; i += 256) {
        int si = i >> 6, d = i & 63, h = d >> 4, dh = d & 15;
        const float* ar = att + (h * S + si) * S;
        float acc = 0.f;
        for (int ti = 0; ti < S; ti++) acc += ar[ti] * qkv[ti * 192 + 128 + h * 16 + dh];
        o_[i] = acc;
    }
    __syncthreads();

    for (int i = tid; i < S * 64; i += 256) {
        int s = i >> 6, d = i & 63;
        float acc = ob[d] + x[i];
        const float4* wr = (const float4*)(ow + d * 64);
        const float4* orow = (const float4*)(o_ + s * 64);
        #pragma unroll
        for (int k = 0; k < 16; k++) {
            float4 w4 = wr[k], ov = orow[k];
            acc += w4.x * ov.x + w4.y * ov.y + w4.z * ov.z + w4.w * ov.w;
        }
        y2[i] = acc;
    }
    __syncthreads();

    if (tid < S) {
        const float* yr = y2 + tid * 64;
        float m = 0.f;
        for (int k = 0; k < 64; k++) m += yr[k];
        m *= (1.f / 64.f);
        float v = 0.f;
        for (int k = 0; k < 64; k++) { float df = yr[k] - m; v += df * df; }
        rm[tid] = m;
        rr[tid] = 1.f / sqrtf(v * (1.f / 64.f) + EPS_);
    }
    __syncthreads();
    for (int i = tid; i < S * 64; i += 256) {
        int s = i >> 6, d = i & 63;
        xps[i] = (y2[i] - rm[s]) * rr[s] * l1w[d] + l1b[d];
    }
    __syncthreads();

    // FFN1-l0: this block's 16 hidden units, all S rows
    {
        const int jl = tid >> 4, kp = tid & 15;
        const int j = bid * 16 + jl;
        float4 w4 = ((const float4*)(f1w + (size_t)j * 64))[kp];
        float b1 = f1b[j];
        for (int s = 0; s < S; s++) {
            float4 xv = ((const float4*)(xps + s * 64))[kp];
            float p = w4.x * xv.x + w4.y * xv.y + w4.z * xv.z + w4.w * xv.w;
            p += __shfl_xor(p, 1);
            p += __shfl_xor(p, 2);
            p += __shfl_xor(p, 4);
            p += __shfl_xor(p, 8);
            if (kp == 0) hbuf[s * 2048 + j] = fmaxf(p + b1, 0.f);
        }
    }
    grid_barrier(bar, base + NBLK_);

    // ---------------- Phase B: FFN2-l0 ----------------
    {
        const int d = bid & 63, half = bid >> 6;
        const int sh = (S + 1) >> 1;
        const int s0 = half * sh, s1 = (half ? S : sh);
        const float4* w4p = (const float4*)(f2w + (size_t)d * 2048 + tid * 8);
        float4 w0 = w4p[0], w1 = w4p[1];
        for (int s = s0; s < s1; s++) {
            const float4* h4 = (const float4*)(hbuf + s * 2048 + tid * 8);
            float4 h0 = h4[0], h1 = h4[1];
            float p = w0.x * h0.x + w0.y * h0.y + w0.z * h0.z + w0.w * h0.w
                    + w1.x * h1.x + w1.y * h1.y + w1.z * h1.z + w1.w * h1.w;
            #pragma unroll
            for (int o = 1; o < 64; o <<= 1) p += __shfl_xor(p, o);
            if ((tid & 63) == 0) wm[tid >> 6] = __float_as_uint(p);  // reuse wm as scratch
            __syncthreads();
            if (tid == 0) {
                float v = __uint_as_float((u32)wm[0]) + __uint_as_float((u32)wm[1])
                        + __uint_as_float((u32)wm[2]) + __uint_as_float((u32)wm[3]);
                y0[s * 64 + d] = v + f2b[d] + xps[s * 64 + d];
            }
            __syncthreads();
        }
    }
    grid_barrier(bar, base + 2 * NBLK_);

    // ---------------- Phase C: layer-1, last row only ----------------
    for (int i = tid; i < S * 64; i += 256) y2[i] = y0[i];
    __syncthreads();
    if (tid < S) {
        const float* yr = y2 + tid * 64;
        float m = 0.f;
        for (int k = 0; k < 64; k++) m += yr[k];
        m *= (1.f / 64.f);
        float v = 0.f;
        for (int k = 0; k < 64; k++) { float df = yr[k] - m; v += df * df; }
        rm[tid] = m;
        rr[tid] = 1.f / sqrtf(v * (1.f / 64.f) + EPS_);
    }
    __syncthreads();
    for (int i = tid; i < S * 64; i += 256) {
        int s = i >> 6, d = i & 63;
        x[i] = (y2[i] - rm[s]) * rr[s] * l2w[d] + l2b[d];
    }
    __syncthreads();

    const float* ipw1 = ipw + 192 * 64;
    for (int i = tid; i < S * 192; i += 256) {
        int s = i / 192, j = i % 192;
        float acc = ipb[192 + j];
        const float4* wr = (const float4*)(ipw1 + j * 64);
        const float4* xr = (const float4*)(x + s * 64);
        #pragma unroll
        for (int k = 0; k < 16; k++) {
            float4 w4 = wr[k], xv = xr[k];
            acc += w4.x * xv.x + w4.y * xv.y + w4.z * xv.z + w4.w * xv.w;
        }
        qkv[i] = acc;
    }
    __syncthreads();

    for (int i = tid; i < 4 * S; i += 256) {
        int h = i / S, ti = i % S;
        const float* qr = qkv + (S - 1) * 192 + h * 16;
        const float* kr = qkv + ti * 192 + 64 + h * 16;
        float acc = 0.f;
        #pragma unroll
        for (int k = 0; k < 16; k++) acc += qr[k] * kr[k];
        att[h * S + ti] = acc * 0.25f;
    }
    __syncthreads();
    if (tid < 4) {
        float* row = att + tid * S;
        float mx = row[0];
        for (int j = 1; j < S; j++) mx = fmaxf(mx, row[j]);
        float sm = 0.f;
        for (int j = 0; j < S; j++) { float e = expf(row[j] - mx); row[j] = e; sm += e; }
        float inv = 1.f / sm;
        for (int j = 0; j < S; j++) row[j] *= inv;
    }
    __syncthreads();
    if (tid < 64) {
        int h = tid >> 4, dh = tid & 15;
        const float* ar = att + h * S;
        float acc = 0.f;
        for (int ti = 0; ti < S; ti++) acc += ar[ti] * qkv[ti * 192 + 128 + h * 16 + dh];
        o_[tid] = acc;
    }
    __syncthreads();
    if (tid < 64) {
        float acc = ob[64 + tid] + x[(S - 1) * 64 + tid];
        const float* wr = ow + 64 * 64 + tid * 64;
        for (int k = 0; k < 64; k++) acc += o_[k] * wr[k];
        y2[tid] = acc;
    }
    __syncthreads();
    if (tid < 64) {
        float v = y2[tid];
        float m = v;
        #pragma unroll
        for (int o = 1; o < 64; o <<= 1) m += __shfl_xor(m, o);
        m *= (1.f / 64.f);
        float df = v - m;
        float var = df * df;
        #pragma unroll
        for (int o = 1; o < 64; o <<= 1) var += __shfl_xor(var, o);
        float r = 1.f / sqrtf(var * (1.f / 64.f) + EPS_);
        xps[tid] = df * r * l1w[64 + tid] + l1b[64 + tid];
    }
    __syncthreads();

    // FFN1-l1 (last row): this block's 16 hidden units
    {
        const int jl = tid >> 4, kp = tid & 15;
        const int j = bid * 16 + jl;
        float4 w4 = ((const float4*)(f1w + (size_t)(2048 + j) * 64))[kp];
        float4 xv = ((const float4*)xps)[kp];
        float p = w4.x * xv.x + w4.y * xv.y + w4.z * xv.z + w4.w * xv.w;
        p += __shfl_xor(p, 1);
        p += __shfl_xor(p, 2);
        p += __shfl_xor(p, 4);
        p += __shfl_xor(p, 8);
        if (kp == 0) hbuf[j] = fmaxf(p + f1b[2048 + j], 0.f);
    }
    grid_barrier(bar, base + 3 * NBLK_);

    // ---------------- Phase D: FFN2-l1 last row, blocks 0..63 ----------------
    if (bid < 64) {
        const int d = bid;
        const float4* w4p = (const float4*)(f2w + (size_t)(64 + d) * 2048 + tid * 8);
        const float4* h4 = (const float4*)(hbuf + tid * 8);
        float4 w0 = w4p[0], w1 = w4p[1], h0 = h4[0], h1 = h4[1];
        float p = w0.x * h0.x + w0.y * h0.y + w0.z * h0.z + w0.w * h0.w
                + w1.x * h1.x + w1.y * h1.y + w1.z * h1.z + w1.w * h1.w;
        #pragma unroll
        for (int o = 1; o < 64; o <<= 1) p += __shfl_xor(p, o);
        __shared__ float sw[4];
        if ((tid & 63) == 0) sw[tid >> 6] = p;
        __syncthreads();
        if (tid == 0) y_last[d] = sw[0] + sw[1] + sw[2] + sw[3] + f2b[64 + d] + xps[d];
    }
}

// ---------------------------------------------------------------------------
// Step-0 logits: fp32 read (exact) + fused bf16 conversion of item_emb.
// ---------------------------------------------------------------------------
__global__ __launch_bounds__(256) void logits_f32_kernel(
    const float* __restrict__ item_emb, const float* __restrict__ y_last,
    const float* __restrict__ lnw, const float* __restrict__ lnb,
    float* __restrict__ out, u64* __restrict__ cand, u16* __restrict__ emb16)
{
    const int tid = threadIdx.x;
    __shared__ float xl[64];
    if (tid < 64) {
        float v = y_last[tid];
        float m = v;
        #pragma unroll
        for (int o = 1; o < 64; o <<= 1) m += __shfl_xor(m, o);
        m *= (1.f / 64.f);
        float df = v - m;
        float var = df * df;
        #pragma unroll
        for (int o = 1; o < 64; o <<= 1) var += __shfl_xor(var, o);
        float r = 1.f / sqrtf(var * (1.f / 64.f) + EPS_);
        xl[tid] = df * r * lnw[tid] + lnb[tid];
    }
    __syncthreads();

    const int l16 = tid & 15;
    float4 q = ((const float4*)xl)[l16];
    const int group0 = (blockIdx.x * 256 + tid) >> 4;
    const int ngroups = (gridDim.x * 256) >> 4;
    u64 lb = 0ull;

    for (int row = group0; row < V_; row += ngroups) {
        float4 e = ((const float4*)(item_emb + (size_t)row * 64))[l16];
        ushort4 us;
        us.x = f2bf(e.x); us.y = f2bf(e.y); us.z = f2bf(e.z); us.w = f2bf(e.w);
        *(ushort4*)(emb16 + (size_t)row * 64 + l16 * 4) = us;
        float p = q.x * e.x + q.y * e.y + q.z * e.z + q.w * e.w;
        p += __shfl_xor(p, 1);
        p += __shfl_xor(p, 2);
        p += __shfl_xor(p, 4);
        p += __shfl_xor(p, 8);
        if (l16 == 0) {
            out[row] = p;
            u64 pk = pack_best(p, row);
            if (pk > lb) lb = pk;
        }
    }
    #pragma unroll
    for (int o = 1; o < 64; o <<= 1) { u64 x = shfl_xor_u64(lb, o); if (x > lb) lb = x; }
    __shared__ u64 sb[4];
    if ((tid & 63) == 0) sb[tid >> 6] = lb;
    __syncthreads();
    if (tid == 0) {
        u64 b = sb[0];
        for (int i = 1; i < 4; i++) if (sb[i] > b) b = sb[i];
        cand[blockIdx.x] = b;
    }
}

// ---------------------------------------------------------------------------
// Steps 1..9 logits from bf16 copy: 8 lanes/row, uint4 (16B) loads.
// ---------------------------------------------------------------------------
__global__ __launch_bounds__(256) void logits_bf16_kernel(
    const u16* __restrict__ emb16, const float* __restrict__ y_last,
    const float* __restrict__ lnw, const float* __restrict__ lnb,
    float* __restrict__ out, u64* __restrict__ cand)
{
    const int tid = threadIdx.x;
    __shared__ float xl[64];
    if (tid < 64) {
        float v = y_last[tid];
        float m = v;
        #pragma unroll
        for (int o = 1; o < 64; o <<= 1) m += __shfl_xor(m, o);
        m *= (1.f / 64.f);
        float df = v - m;
        float var = df * df;
        #pragma unroll
        for (int o = 1; o < 64; o <<= 1) var += __shfl_xor(var, o);
        float r = 1.f / sqrtf(var * (1.f / 64.f) + EPS_);
        xl[tid] = df * r * lnw[tid] + lnb[tid];
    }
    __syncthreads();

    const int j8 = tid & 7;
    float q[8];
    #pragma unroll
    for (int i = 0; i < 8; i++) q[i] = xl[j8 * 8 + i];
    const int group0 = (blockIdx.x * 256 + tid) >> 3;
    const int ngroups = (gridDim.x * 256) >> 3;
    const uint4* base = (const uint4*)emb16;
    u64 lb = 0ull;

    for (int row = group0; row < V_; row += ngroups) {
        uint4 u = base[(size_t)row * 8 + j8];
        float p = q[0] * bf_lo(u.x) + q[1] * bf_hi(u.x)
                + q[2] * bf_lo(u.y) + q[3] * bf_hi(u.y)
                + q[4] * bf_lo(u.z) + q[5] * bf_hi(u.z)
                + q[6] * bf_lo(u.w) + q[7] * bf_hi(u.w);
        p += __shfl_xor(p, 1);
        p += __shfl_xor(p, 2);
        p += __shfl_xor(p, 4);
        if (j8 == 0) {
            out[row] = p;
            u64 pk = pack_best(p, row);
            if (pk > lb) lb = pk;
        }
    }
    #pragma unroll
    for (int o = 1; o < 64; o <<= 1) { u64 x = shfl_xor_u64(lb, o); if (x > lb) lb = x; }
    __shared__ u64 sb[4];
    if ((tid & 63) == 0) sb[tid >> 6] = lb;
    __syncthreads();
    if (tid == 0) {
        u64 b = sb[0];
        for (int i = 1; i < 4; i++) if (sb[i] > b) b = sb[i];
        cand[blockIdx.x] = b;
    }
}

__global__ __launch_bounds__(256) void finalize_kernel(
    const u64* __restrict__ cand, const float* __restrict__ item_emb,
    const float* __restrict__ y_last,
    const float* __restrict__ lnw, const float* __restrict__ lnb,
    float* __restrict__ gen_out)
{
    __shared__ float xl[64];
    __shared__ int list[64], cnt;
    __shared__ u64 wm[4], best;
    int r = resolve_argmax(cand, item_emb, y_last, lnw, lnb, xl, list, wm, &cnt, &best);
    if (threadIdx.x == 0) gen_out[STEPS_ - 1] = (float)r;
}

extern "C" void kernel_launch(void* const* d_in, const int* in_sizes, int n_in,
                              void* d_out, int out_size, void* d_ws, size_t ws_size,
                              hipStream_t stream) {
    const float* ht       = (const float*)d_in[0];
    const float* item_emb = (const float*)d_in[1];
    const float* pos_emb  = (const float*)d_in[2];
    const float* ipw      = (const float*)d_in[3];
    const float* ipb      = (const float*)d_in[4];
    const float* ow       = (const float*)d_in[5];
    const float* ob       = (const float*)d_in[6];
    const float* l1w      = (const float*)d_in[7];
    const float* l1b      = (const float*)d_in[8];
    const float* l2w      = (const float*)d_in[9];
    const float* l2b      = (const float*)d_in[10];
    const float* f1w      = (const float*)d_in[11];
    const float* f1b      = (const float*)d_in[12];
    const float* f2w      = (const float*)d_in[13];
    const float* f2b      = (const float*)d_in[14];

    float* out = (float*)d_out;
    char* ws = (char*)d_ws;
    int*   gen_idx = (int*)ws;                 // [0,64)
    u32*   bar     = (u32*)(ws + 128);         // barrier counter
    float* y_last  = (float*)(ws + 256);       // 64 f
    float* y0      = (float*)(ws + 512);       // 10x64 f
    float* hbuf    = (float*)(ws + 4096);      // 10x2048 f (80KB)
    u64*   cand    = (u64*)(ws + 90112);       // 2048 u64
    u16*   emb16   = (u16*)(ws + 131072);      // 128 MB bf16 item_emb
    float* gen_out = out + (size_t)STEPS_ * V_;

    init_kernel<<<1, 64, 0, stream>>>(bar);
    for (int t = 0; t < STEPS_; t++) {
        encoder_kernel<<<NBLK_, 256, 0, stream>>>(
            ht, item_emb, pos_emb, ipw, ipb, ow, ob, l1w, l1b, l2w, l2b,
            f1w, f1b, f2w, f2b, cand, gen_idx, gen_out, y0, y_last, hbuf, bar, t);
        if (t == 0)
            logits_f32_kernel<<<2048, 256, 0, stream>>>(
                item_emb, y_last, l2w + 64, l2b + 64, out, cand, emb16);
        else
            logits_bf16_kernel<<<2048, 256, 0, stream>>>(
                emb16, y_last, l2w + 64, l2b + 64, out + (size_t)t * V_, cand);
    }
    finalize_kernel<<<1, 256, 0, stream>>>(
        cand, item_emb, y_last, l2w + 64, l2b + 64, gen_out);
}